// Round 10
// baseline (117.198 us; speedup 1.0000x reference)
//
#include <hip/hip_runtime.h>
#include <hip/hip_bf16.h>
#include <hip/hip_fp16.h>

// Problem constants (fixed by setup_inputs)
#define BATCH 16
#define NCH 3
#define H 512
#define W 512
#define HW (H * W)          // 262144 = 2^18
#define PAD 7
#define K 26                // int(0.0001 * 512 * 512)
#define NSUB2 2048          // subs (4 rows x 32 cols = 128 px) per batch
#define NPAIR 32            // 2 maps x 16 batches
#define BK (BATCH * K)      // 416
#define CAP 32768           // candidate list capacity per pair
#define LDSCAP 6144         // merge LDS tile (48 KB)

#define ROWS1 46            // pool tile rows: 32 + 14
#define SHP 36              // padded LDS stride (32 cols used)

#define FINF __builtin_inff()

// monotone float->u32 key (order-preserving for all floats)
__device__ __forceinline__ unsigned mkey(float f) {
    unsigned u = __float_as_uint(f);
    unsigned m = (unsigned)(((int)u) >> 31) | 0x80000000u;
    return u ^ m;
}

__device__ __forceinline__ unsigned short f2h(float f) {
    __half h = __float2half(f);
    return *reinterpret_cast<unsigned short*>(&h);
}
__device__ __forceinline__ float h2f(unsigned short s) {
    __half h = *reinterpret_cast<__half*>(&s);
    return __half2float(h);
}

__device__ __forceinline__ unsigned long long shfl_xor_u64(unsigned long long v, int m) {
    int lo = __shfl_xor((int)(unsigned)(v & 0xFFFFFFFFull), m);
    int hi = __shfl_xor((int)(unsigned)(v >> 32), m);
    return ((unsigned long long)(unsigned)hi << 32) | (unsigned)lo;
}

template <bool MX>
__device__ __forceinline__ float op(float a, float b) { return MX ? fmaxf(a, b) : fminf(a, b); }
template <bool MX>
__device__ __forceinline__ float4 op4(float4 a, float4 b) {
    return make_float4(op<MX>(a.x, b.x), op<MX>(a.y, b.y), op<MX>(a.z, b.z), op<MX>(a.w, b.w));
}

// horizontal 15-window pool of a 4-output group from 5 clamped-base float4s
template <bool MX>
__device__ __forceinline__ float4 hquad(float4 fA, float4 fB, float4 fC, float4 fD, float4 fE) {
    float4 m4 = op4<MX>(op4<MX>(fB, fC), fD);
    float tm = op<MX>(op<MX>(m4.x, m4.y), op<MX>(m4.z, m4.w));
    return make_float4(
        op<MX>(tm, op<MX>(fA.y, op<MX>(fA.z, fA.w))),
        op<MX>(tm, op<MX>(fA.z, op<MX>(fA.w, fE.x))),
        op<MX>(tm, op<MX>(fA.w, op<MX>(fE.x, fE.y))),
        op<MX>(tm, op<MX>(fE.x, op<MX>(fE.y, fE.z))));
}

// v-pool of 2 consecutive output rows from 16 LDS rows (14-row shared core)
template <bool MX>
__device__ __forceinline__ void vpool2(const float* __restrict__ sH, int vy, int vx,
                                       float4 o[2]) {
    const float* p0 = sH + vy * SHP + vx;
    float4 t4 = *(const float4*)(p0 + SHP);
#pragma unroll
    for (int j = 2; j <= 14; ++j) t4 = op4<MX>(t4, *(const float4*)(p0 + j * SHP));
    float4 r0 = *(const float4*)(p0);
    float4 r15 = *(const float4*)(p0 + 15 * SHP);
    o[0] = op4<MX>(r0, t4);
    o[1] = op4<MX>(t4, r15);
}

// ---------------------------------------------------------------------------
// K1: per 32x32 tile (grid 4096 = 8/CU x 256 CU x 2 exact rounds). Per
// channel: h-pool straight from global (5 clamped-base float4 loads per
// 4-output group == exact clamp-to-edge), max AND min from the same loads
// into two LDS buffers (13.2 KB total); x->out copy rides on the center
// float4. v-pool half-split: u<128 -> max map (fp16 Vmax store + bc subkeys),
// u>=128 -> min map (dc subkeys). NO per-pixel key maps (recomputed later for
// qualifying subs only). Sub = 4 rows x 32 cols.
__global__ __launch_bounds__(256, 8) void pool_maps_kernel(
    const float* __restrict__ x, unsigned short* __restrict__ vmaxh,
    unsigned* __restrict__ subkey, float* __restrict__ out) {
    __shared__ __align__(16) float sHmax[ROWS1 * SHP];
    __shared__ __align__(16) float sHmin[ROWS1 * SHP];
    int blk = blockIdx.x;
    int b = blk >> 8;
    int tile = blk & 255;
    int tx0 = (tile & 15) << 5;
    int ty0 = (tile >> 4) << 5;
    int u = threadIdx.x;
    int half = u >> 7;      // 0: max map (bc + Vmax), 1: min map (dc)
    int v = u & 127;
    int rg = v >> 3;        // 0..15 row-pairs
    int cg = v & 7;         // 0..7 col-groups
    int vx = cg << 2;
    int vy = rg << 1;
    float4 acc[2];
    float ainit = half ? FINF : -FINF;
    acc[0] = acc[1] = make_float4(ainit, ainit, ainit, ainit);

    for (int c = 0; c < NCH; ++c) {
        const float* xp = x + (((size_t)(b * NCH + c)) << 18);
        float* outp = out + (((size_t)(b * 4 + c)) << 18);
        for (int it = u; it < ROWS1 * 8; it += 256) {
            int r = it >> 3;
            int x0 = (it & 7) << 2;
            int gy = ty0 - PAD + r;
            gy = gy < 0 ? 0 : (gy > H - 1 ? H - 1 : gy);
            const float* rowp = xp + (gy << 9);
            int gx0 = tx0 + x0;
            int aB = gx0 - 8; aB = aB < 0 ? 0 : aB;
            int bB = gx0 - 4; bB = bB < 0 ? 0 : bB;
            int dB = gx0 + 4; dB = dB > W - 4 ? W - 4 : dB;
            int eB = gx0 + 8; eB = eB > W - 4 ? W - 4 : eB;
            float4 fA = *(const float4*)(rowp + aB);
            float4 fB = *(const float4*)(rowp + bB);
            float4 fC = *(const float4*)(rowp + gx0);
            float4 fD = *(const float4*)(rowp + dB);
            float4 fE = *(const float4*)(rowp + eB);
            if (r >= PAD && r < PAD + 32)
                *(float4*)&outp[((ty0 + r - PAD) << 9) + gx0] = fC;
            *(float4*)&sHmax[r * SHP + x0] = hquad<true>(fA, fB, fC, fD, fE);
            *(float4*)&sHmin[r * SHP + x0] = hquad<false>(fA, fB, fC, fD, fE);
        }
        __syncthreads();
        if (half == 0) {
            float4 o[2];
            vpool2<true>(sHmax, vy, vx, o);
            unsigned short* vp = vmaxh + (((size_t)(b * NCH + c)) << 18);
            int gbase = ((ty0 + vy) << 9) + tx0 + vx;
            *(ushort4*)&vp[gbase] = make_ushort4(f2h(o[0].x), f2h(o[0].y), f2h(o[0].z), f2h(o[0].w));
            *(ushort4*)&vp[gbase + 512] = make_ushort4(f2h(o[1].x), f2h(o[1].y), f2h(o[1].z), f2h(o[1].w));
            acc[0] = op4<true>(acc[0], o[0]);
            acc[1] = op4<true>(acc[1], o[1]);
        } else {
            float4 o[2];
            vpool2<false>(sHmin, vy, vx, o);
            acc[0] = op4<false>(acc[0], o[0]);
            acc[1] = op4<false>(acc[1], o[1]);
        }
        __syncthreads();
    }
    // subkeys: sub = 4 rows x 32 cols = 16 contiguous lanes (2 row-pairs x 8 cg)
    float red;
    if (half == 0) {   // bc: subkey = max of ~mkey = ~mkey(min of max-map)
        red = fminf(fminf(fminf(acc[0].x, acc[0].y), fminf(acc[0].z, acc[0].w)),
                    fminf(fminf(acc[1].x, acc[1].y), fminf(acc[1].z, acc[1].w)));
#pragma unroll
        for (int s = 1; s < 16; s <<= 1) red = fminf(red, __shfl_xor(red, s));
    } else {           // dc: subkey = mkey(max of min-map)
        red = fmaxf(fmaxf(fmaxf(acc[0].x, acc[0].y), fmaxf(acc[0].z, acc[0].w)),
                    fmaxf(fmaxf(acc[1].x, acc[1].y), fmaxf(acc[1].z, acc[1].w)));
#pragma unroll
        for (int s = 1; s < 16; s <<= 1) red = fmaxf(red, __shfl_xor(red, s));
    }
    if ((v & 15) == 0) {
        int s = rg >> 1;  // 0..7 sub row within tile
        int subid = (((ty0 >> 2) + s) << 4) + (tx0 >> 5);
        if (half == 0) subkey[(BATCH + b) * NSUB2 + subid] = ~mkey(red);
        else           subkey[b * NSUB2 + subid] = mkey(red);
    }
}

// ---------------------------------------------------------------------------
// K2: tau per (map,batch) pair = 26th-largest per-sub key-max over 2048 subs.
// Theorem: the 26 largest sub-maxima sit at 26 distinct pixels, all >= tau,
// so v26 >= tau and every top-26 pixel's sub has subkey >= tau.
// One wave per pair, 32 packed u64/lane. Also zeroes the counter for K3.
__global__ __launch_bounds__(64) void tau_kernel(
    const unsigned* __restrict__ subkey, unsigned* __restrict__ tau,
    int* __restrict__ nCand) {
    int pair = blockIdx.x;
    int lane = threadIdx.x;
    const unsigned* sk = subkey + (size_t)pair * NSUB2 + lane * 32;
    unsigned long long q[32];
#pragma unroll
    for (int j = 0; j < 32; j += 4) {
        uint4 kq = *(const uint4*)&sk[j];
        q[j + 0] = ((unsigned long long)kq.x << 32) | (unsigned)(lane * 32 + j + 0);
        q[j + 1] = ((unsigned long long)kq.y << 32) | (unsigned)(lane * 32 + j + 1);
        q[j + 2] = ((unsigned long long)kq.z << 32) | (unsigned)(lane * 32 + j + 2);
        q[j + 3] = ((unsigned long long)kq.w << 32) | (unsigned)(lane * 32 + j + 3);
    }
    unsigned tv = 0;
    for (int r = 0; r < K; ++r) {
        unsigned long long b0 = q[0], b1 = q[1], b2 = q[2], b3 = q[3];
#pragma unroll
        for (int j = 4; j < 32; j += 4) {
            b0 = q[j] > b0 ? q[j] : b0;
            b1 = q[j + 1] > b1 ? q[j + 1] : b1;
            b2 = q[j + 2] > b2 ? q[j + 2] : b2;
            b3 = q[j + 3] > b3 ? q[j + 3] : b3;
        }
        b0 = b1 > b0 ? b1 : b0;
        b2 = b3 > b2 ? b3 : b2;
        unsigned long long m = b2 > b0 ? b2 : b0;
#pragma unroll
        for (int s = 1; s < 64; s <<= 1) {
            unsigned long long o = shfl_xor_u64(m, s);
            m = o > m ? o : m;
        }
        if (r == K - 1) tv = (unsigned)(m >> 32);
#pragma unroll
        for (int j = 0; j < 32; ++j)
            if (q[j] == m) q[j] = 0;
    }
    if (lane == 0) {
        tau[pair] = tv;
        nCand[pair] = 0;
    }
}

// ---------------------------------------------------------------------------
// K3: recompute+select. Per (pair, slot) block: wave 0 ballot-compacts
// qualifying subs (subkey >= tau) into LDS; then each wave recomputes one
// sub's pooled map from L3-warm x (h-pool into a private LDS strip, v-pool
// per pixel — fmax/fmin are EXACT ops so any reassociation is bitwise equal
// to K1's values) and appends (key,idx) candidates with key >= tau via one
// wave-aggregated atomic. Replaces the 33 MB key maps + full-image filter.
__global__ __launch_bounds__(256) void recompute_select_kernel(
    const float* __restrict__ x, const unsigned* __restrict__ subkey,
    const unsigned* __restrict__ tau, int* __restrict__ nCand,
    unsigned long long* __restrict__ cand) {
    int blk = blockIdx.x;        // 512 = 32 pairs x 16 slots
    int pair = blk >> 4;
    int bslot = blk & 15;
    int map = pair >> 4, b = pair & 15;
    int t = threadIdx.x;
    int wv = t >> 6, lane = t & 63;
    __shared__ int sList[NSUB2];
    __shared__ int sN;
    __shared__ __align__(16) float sW[4][18 * SHP];
    unsigned tv = tau[pair];
    if (wv == 0) {
        const unsigned* sk = subkey + (size_t)pair * NSUB2;
        int base = 0;
        for (int j0 = 0; j0 < NSUB2; j0 += 64) {
            unsigned k = sk[j0 + lane];
            bool q = k >= tv;
            unsigned long long mk = __ballot(q);
            if (q) sList[base + __popcll(mk & ((1ull << lane) - 1ull))] = j0 + lane;
            base += (int)__popcll(mk);
        }
        if (lane == 0) sN = base;
    }
    __syncthreads();
    int n = sN;
    float* sH = sW[wv];
    unsigned long long* cp = cand + (size_t)pair * CAP;
    const float* xb = x + (((size_t)(b * NCH)) << 18);
    for (int si = bslot * 4 + wv; si < n; si += 64) {
        int sub = sList[si];
        int srow = sub >> 4, scol = sub & 15;
        int ys = srow << 2, xs = scol << 5;
        float vacc0 = map ? -FINF : FINF;
        float vacc1 = vacc0;
        for (int c = 0; c < NCH; ++c) {
            const float* xp = xb + (((size_t)c) << 18);
            // h-pool stage: 18 rows x 8 groups (wave-private LDS strip)
            for (int it = lane; it < 18 * 8; it += 64) {
                int r = it >> 3;
                int x0 = (it & 7) << 2;
                int gy = ys - PAD + r;
                gy = gy < 0 ? 0 : (gy > H - 1 ? H - 1 : gy);
                const float* rowp = xp + (gy << 9);
                int gx0 = xs + x0;
                int aB = gx0 - 8; aB = aB < 0 ? 0 : aB;
                int bB = gx0 - 4; bB = bB < 0 ? 0 : bB;
                int dB = gx0 + 4; dB = dB > W - 4 ? W - 4 : dB;
                int eB = gx0 + 8; eB = eB > W - 4 ? W - 4 : eB;
                float4 fA = *(const float4*)(rowp + aB);
                float4 fB = *(const float4*)(rowp + bB);
                float4 fC = *(const float4*)(rowp + gx0);
                float4 fD = *(const float4*)(rowp + dB);
                float4 fE = *(const float4*)(rowp + eB);
                float4 hq = map ? hquad<true>(fA, fB, fC, fD, fE)
                                : hquad<false>(fA, fB, fC, fD, fE);
                *(float4*)&sH[r * SHP + x0] = hq;
            }
            // wave-internal LDS RAW: in-order DS pipe + compiler waitcnt
            {
                int pr0 = lane >> 5, pc = lane & 31;
                float m0 = sH[pr0 * SHP + pc];
                float m1 = sH[(pr0 + 2) * SHP + pc];
#pragma unroll
                for (int jj = 1; jj < 15; ++jj) {
                    if (map) {
                        m0 = fmaxf(m0, sH[(pr0 + jj) * SHP + pc]);
                        m1 = fmaxf(m1, sH[(pr0 + 2 + jj) * SHP + pc]);
                    } else {
                        m0 = fminf(m0, sH[(pr0 + jj) * SHP + pc]);
                        m1 = fminf(m1, sH[(pr0 + 2 + jj) * SHP + pc]);
                    }
                }
                if (map) { vacc0 = fmaxf(vacc0, m0); vacc1 = fmaxf(vacc1, m1); }
                else     { vacc0 = fminf(vacc0, m0); vacc1 = fminf(vacc1, m1); }
            }
        }
        // append candidates with key >= tau (one atomic per wave)
        unsigned k0 = map ? ~mkey(vacc0) : mkey(vacc0);
        unsigned k1 = map ? ~mkey(vacc1) : mkey(vacc1);
        bool q0 = k0 >= tv, q1 = k1 >= tv;
        unsigned long long m0 = __ballot(q0);
        unsigned long long m1 = __ballot(q1);
        int c0 = (int)__popcll(m0);
        int tot = c0 + (int)__popcll(m1);
        int basep = 0;
        if (lane == 0 && tot) basep = atomicAdd(&nCand[pair], tot);
        basep = __shfl(basep, 0);
        unsigned long long lt = (1ull << lane) - 1ull;
        int pr0 = lane >> 5, pc = lane & 31;
        if (q0) {
            int slot = basep + (int)__popcll(m0 & lt);
            int p = ((ys + pr0) << 9) + xs + pc;
            if (slot < CAP)
                cp[slot] = ((unsigned long long)k0 << 32) | (unsigned)(0x7FFFFFFF - p);
        }
        if (q1) {
            int slot = basep + c0 + (int)__popcll(m1 & lt);
            int p = ((ys + pr0 + 2) << 9) + xs + pc;
            if (slot < CAP)
                cp[slot] = ((unsigned long long)k1 << 32) | (unsigned)(0x7FFFFFFF - p);
        }
    }
}

// ---------------------------------------------------------------------------
// K4: per-pair merge of nCand candidates -> global top-26. LDS-tiled with a
// CACHED per-thread slice max: per round only the winner's owner rescans.
// Unique u64s => equality removes exactly one entry.
// map0 (dc): A1 (argmax of per-pixel channel max, first occurrence).
// map1 (bc): the 26 indices for A2.
__global__ __launch_bounds__(256) void merge_kernel(
    const unsigned long long* __restrict__ cand, const int* __restrict__ nCand,
    const float* __restrict__ img, float* __restrict__ A1, int* __restrict__ idx2all) {
    int pair = blockIdx.x;
    int map = pair >> 4, b = pair & 15;
    int t = threadIdx.x;
    int wv = t >> 6, lane = t & 63;
    int n = nCand[pair];
    n = n < CAP ? n : CAP;
    const unsigned long long* cp = cand + (size_t)pair * CAP;
    __shared__ unsigned long long sC[LDSCAP];
    __shared__ unsigned long long sB[4];
    __shared__ unsigned long long sWin[K];
    __shared__ float sM[K];
    int ntile = (n + LDSCAP - 1) / LDSCAP;
    unsigned long long kc = 0;
    for (int tl = 0; tl < ntile; ++tl) {
        int lo = tl * LDSCAP;
        int m = n - lo; m = m > LDSCAP ? LDSCAP : m;
        for (int i = t; i < m; i += 256) sC[i] = cp[lo + i];
        if (tl > 0) kc = (t < K) ? sWin[t] : 0ull;
        __syncthreads();
        unsigned long long lm = 0;
        int slot = -1;
        for (int i = t; i < m; i += 256) {
            unsigned long long v = sC[i];
            if (v > lm) { lm = v; slot = i; }
        }
        for (int r = 0; r < K; ++r) {
            unsigned long long mm = lm > kc ? lm : kc;
#pragma unroll
            for (int s = 1; s < 64; s <<= 1) {
                unsigned long long o = shfl_xor_u64(mm, s);
                mm = o > mm ? o : mm;
            }
            if (lane == 0) sB[wv] = mm;
            __syncthreads();
            unsigned long long wb = sB[0];
            if (sB[1] > wb) wb = sB[1];
            if (sB[2] > wb) wb = sB[2];
            if (sB[3] > wb) wb = sB[3];
            if (t == 0) sWin[r] = wb;
            if (wb == lm) {                 // owner: remove + rescan own slice
                sC[slot] = 0ull;
                lm = 0; slot = -1;
                for (int i = t; i < m; i += 256) {
                    unsigned long long v = sC[i];
                    if (v > lm) { lm = v; slot = i; }
                }
            }
            if (wb == kc) kc = 0ull;
            __syncthreads();
        }
    }
    if (map == 0) {
        if (t < K) {
            int p = 0x7FFFFFFF - (int)(unsigned)(sWin[t] & 0xFFFFFFFFull);
            float m = img[(((size_t)(b * NCH + 0)) << 18) + p];
            m = fmaxf(m, img[(((size_t)(b * NCH + 1)) << 18) + p]);
            m = fmaxf(m, img[(((size_t)(b * NCH + 2)) << 18) + p]);
            sM[t] = m;
        }
        __syncthreads();
        if (t == 0) {
            float bm = -FINF;
            int bj = 0;
            for (int j = 0; j < K; ++j)
                if (sM[j] > bm) { bm = sM[j]; bj = j; }   // strict > = first occurrence
            int p = 0x7FFFFFFF - (int)(unsigned)(sWin[bj] & 0xFFFFFFFFull);
#pragma unroll
            for (int c = 0; c < NCH; ++c)
                A1[b * NCH + c] = img[(((size_t)(b * NCH + c)) << 18) + p];
        }
    } else {
        if (t < K)
            idx2all[b * K + t] = 0x7FFFFFFF - (int)(unsigned)(sWin[t] & 0xFFFFFFFFull);
    }
}

// ---------------------------------------------------------------------------
// K5: A2 (mean over ALL batches' bottom-k indices — faithful to the
// reference's batch-mixing bug), A = 0.75*A1 + 0.25*A2, d = (1 - A) + 1e-6
__global__ __launch_bounds__(256) void compute_A_kernel(
    const float* __restrict__ img, const int* __restrict__ idx2all,
    const float* __restrict__ A1, float* __restrict__ dvec) {
    int b = blockIdx.x;
    __shared__ float ssum[256];
    for (int c = 0; c < NCH; ++c) {
        float s = 0.0f;
        for (int j = threadIdx.x; j < BK; j += 256)
            s += img[(((size_t)(b * NCH + c)) << 18) + idx2all[j]];
        ssum[threadIdx.x] = s;
        __syncthreads();
        for (int st = 128; st > 0; st >>= 1) {
            if (threadIdx.x < st) ssum[threadIdx.x] += ssum[threadIdx.x + st];
            __syncthreads();
        }
        if (threadIdx.x == 0) {
            float A2 = ssum[0] / (float)BK;
            float A = 0.75f * A1[b * NCH + c] + 0.25f * A2;
            dvec[b * NCH + c] = (1.0f - A) + 1e-6f;
        }
        __syncthreads();
    }
}

// ---------------------------------------------------------------------------
// K6: t = 1 - 0.95 * min_c (1 - M_c)*r_c, streaming fp16 Vmax (25 MB read,
// 17 MB write). x-channels of out were already written by pool_maps.
__global__ __launch_bounds__(256) void final_t_kernel(
    const unsigned short* __restrict__ vmaxh, const float* __restrict__ dvec,
    float* __restrict__ out) {
    int i4 = (blockIdx.x * 256 + threadIdx.x) << 2;
    int b = i4 >> 18;
    int p = i4 & (HW - 1);
    const unsigned short* vp = vmaxh + (((size_t)(b * NCH)) << 18) + p;
    float r0 = 1.0f / dvec[b * NCH + 0];
    float r1 = 1.0f / dvec[b * NCH + 1];
    float r2 = 1.0f / dvec[b * NCH + 2];
    ushort4 v0 = *(const ushort4*)(vp);
    ushort4 v1 = *(const ushort4*)(vp + (1 << 18));
    ushort4 v2 = *(const ushort4*)(vp + (2 << 18));
    float4 t;
    t.x = 1.0f - 0.95f * fminf(fminf(fmaf(-h2f(v0.x), r0, r0), fmaf(-h2f(v1.x), r1, r1)),
                               fmaf(-h2f(v2.x), r2, r2));
    t.y = 1.0f - 0.95f * fminf(fminf(fmaf(-h2f(v0.y), r0, r0), fmaf(-h2f(v1.y), r1, r1)),
                               fmaf(-h2f(v2.y), r2, r2));
    t.z = 1.0f - 0.95f * fminf(fminf(fmaf(-h2f(v0.z), r0, r0), fmaf(-h2f(v1.z), r1, r1)),
                               fmaf(-h2f(v2.z), r2, r2));
    t.w = 1.0f - 0.95f * fminf(fminf(fmaf(-h2f(v0.w), r0, r0), fmaf(-h2f(v1.w), r1, r1)),
                               fmaf(-h2f(v2.w), r2, r2));
    *(float4*)&out[(((size_t)(b * 4 + 3)) << 18) + p] = t;
}

// ---------------------------------------------------------------------------
extern "C" void kernel_launch(void* const* d_in, const int* in_sizes, int n_in,
                              void* d_out, int out_size, void* d_ws, size_t ws_size,
                              hipStream_t stream) {
    const float* x = (const float*)d_in[0];
    float* out = (float*)d_out;

    const size_t nPix = (size_t)BATCH * HW;      // 4,194,304
    const size_t nCh = (size_t)BATCH * NCH * HW; // 12,582,912

    unsigned long long* cand = (unsigned long long*)d_ws;        // 8 MB
    unsigned short* vmaxh = (unsigned short*)(cand + (size_t)NPAIR * CAP); // 24 MB fp16
    unsigned* subkey = (unsigned*)(vmaxh + nCh);                 // [2][16][2048]
    unsigned* tau = subkey + (size_t)2 * BATCH * NSUB2;
    int* nCand = (int*)(tau + NPAIR);
    float* A1 = (float*)(nCand + NPAIR);
    int* idx2all = (int*)(A1 + BATCH * NCH);
    float* dvec = (float*)(idx2all + BK);

    pool_maps_kernel<<<BATCH * 256, 256, 0, stream>>>(x, vmaxh, subkey, out);
    tau_kernel<<<NPAIR, 64, 0, stream>>>(subkey, tau, nCand);
    recompute_select_kernel<<<NPAIR * 16, 256, 0, stream>>>(x, subkey, tau, nCand, cand);
    merge_kernel<<<NPAIR, 256, 0, stream>>>(cand, nCand, x, A1, idx2all);
    compute_A_kernel<<<BATCH, 256, 0, stream>>>(x, idx2all, A1, dvec);
    final_t_kernel<<<(int)(nPix / 4 / 256), 256, 0, stream>>>(vmaxh, dvec, out);
}

// Round 11
// 107.005 us; speedup vs baseline: 1.0953x; 1.0953x over previous
//
#include <hip/hip_runtime.h>
#include <hip/hip_bf16.h>
#include <hip/hip_fp16.h>

// Problem constants (fixed by setup_inputs)
#define BATCH 16
#define NCH 3
#define H 512
#define W 512
#define HW (H * W)          // 262144 = 2^18
#define PAD 7
#define K 26                // int(0.0001 * 512 * 512)
#define NSUB 1024           // subs (4 rows x 64 cols = 256 px) per batch
#define NPAIR 32            // 2 maps x 16 batches
#define BK (BATCH * K)      // 416
#define CAP 32768           // candidate list capacity per pair
#define LDSCAP 6144         // merge LDS tile (48 KB)

#define TH1 32              // pool tile height
#define ROWS1 46            // TH1 + 14
#define SHP 68              // padded LDS stride for h-pool rows (64 used)

#define FINF __builtin_inff()

// monotone float->u32 key (order-preserving for all floats)
__device__ __forceinline__ unsigned mkey(float f) {
    unsigned u = __float_as_uint(f);
    unsigned m = (unsigned)(((int)u) >> 31) | 0x80000000u;
    return u ^ m;
}

__device__ __forceinline__ unsigned short f2h(float f) {
    __half h = __float2half(f);
    return *reinterpret_cast<unsigned short*>(&h);
}
__device__ __forceinline__ float h2f(unsigned short s) {
    __half h = *reinterpret_cast<__half*>(&s);
    return __half2float(h);
}

__device__ __forceinline__ unsigned long long shfl_xor_u64(unsigned long long v, int m) {
    int lo = __shfl_xor((int)(unsigned)(v & 0xFFFFFFFFull), m);
    int hi = __shfl_xor((int)(unsigned)(v >> 32), m);
    return ((unsigned long long)(unsigned)hi << 32) | (unsigned)lo;
}

template <bool MX>
__device__ __forceinline__ float op(float a, float b) { return MX ? fmaxf(a, b) : fminf(a, b); }
template <bool MX>
__device__ __forceinline__ float4 op4(float4 a, float4 b) {
    return make_float4(op<MX>(a.x, b.x), op<MX>(a.y, b.y), op<MX>(a.z, b.z), op<MX>(a.w, b.w));
}

// horizontal 15-window pool of a 4-output group from 5 clamped-base float4s
template <bool MX>
__device__ __forceinline__ float4 hquad(float4 fA, float4 fB, float4 fC, float4 fD, float4 fE) {
    float4 m4 = op4<MX>(op4<MX>(fB, fC), fD);
    float tm = op<MX>(op<MX>(m4.x, m4.y), op<MX>(m4.z, m4.w));
    return make_float4(
        op<MX>(tm, op<MX>(fA.y, op<MX>(fA.z, fA.w))),
        op<MX>(tm, op<MX>(fA.z, op<MX>(fA.w, fE.x))),
        op<MX>(tm, op<MX>(fA.w, op<MX>(fE.x, fE.y))),
        op<MX>(tm, op<MX>(fE.x, op<MX>(fE.y, fE.z))));
}

// v-pool of one map half: 18 LDS rows -> 4 output rows; optional fp16 global
// write of the per-channel window max (for the final t kernel).
template <bool MX, bool WR>
__device__ __forceinline__ void vpool_half(const float* __restrict__ sH, int vy, int vx,
                                           float4 acc[4], unsigned short* __restrict__ vp,
                                           int gbase) {
    const float* p0 = sH + vy * SHP + vx;
    float4 t4 = *(const float4*)(p0 + 3 * SHP);
#pragma unroll
    for (int j = 4; j <= 14; ++j) t4 = op4<MX>(t4, *(const float4*)(p0 + j * SHP));
    float4 a0 = *(const float4*)(p0);
    float4 a1 = *(const float4*)(p0 + SHP);
    float4 a2 = *(const float4*)(p0 + 2 * SHP);
    float4 b15 = *(const float4*)(p0 + 15 * SHP);
    float4 b16 = *(const float4*)(p0 + 16 * SHP);
    float4 b17 = *(const float4*)(p0 + 17 * SHP);
    float4 o0 = op4<MX>(op4<MX>(a0, a1), op4<MX>(a2, t4));
    float4 o1 = op4<MX>(op4<MX>(a1, a2), op4<MX>(t4, b15));
    float4 o2 = op4<MX>(op4<MX>(a2, t4), op4<MX>(b15, b16));
    float4 o3 = op4<MX>(op4<MX>(t4, b15), op4<MX>(b16, b17));
    if (WR) {
        *(ushort4*)&vp[gbase] = make_ushort4(f2h(o0.x), f2h(o0.y), f2h(o0.z), f2h(o0.w));
        *(ushort4*)&vp[gbase + 512] = make_ushort4(f2h(o1.x), f2h(o1.y), f2h(o1.z), f2h(o1.w));
        *(ushort4*)&vp[gbase + 1024] = make_ushort4(f2h(o2.x), f2h(o2.y), f2h(o2.z), f2h(o2.w));
        *(ushort4*)&vp[gbase + 1536] = make_ushort4(f2h(o3.x), f2h(o3.y), f2h(o3.z), f2h(o3.w));
    }
    acc[0] = op4<MX>(acc[0], o0);
    acc[1] = op4<MX>(acc[1], o1);
    acc[2] = op4<MX>(acc[2], o2);
    acc[3] = op4<MX>(acc[3], o3);
}

// ---------------------------------------------------------------------------
// K1 (r9 structure, key-map stores removed): per 64x32 tile, per channel:
// h-pool straight from global (5 clamped-base float4 loads per 4-output group
// == exact clamp-to-edge), max AND min from the same loads into two LDS
// buffers; x->out copy rides on the center float4. v-pool half-split:
// u<128 -> max map (fp16 Vmax store + bc subkeys), u>=128 -> min map (dc
// subkeys). Per-pixel keys are NOT stored (recomputed for qualifying subs).
__global__ __launch_bounds__(256, 6) void pool_maps_kernel(
    const float* __restrict__ x, unsigned short* __restrict__ vmaxh,
    unsigned* __restrict__ subkey, float* __restrict__ out) {
    __shared__ __align__(16) float sHmax[ROWS1 * SHP];
    __shared__ __align__(16) float sHmin[ROWS1 * SHP];
    int blk = blockIdx.x;
    int b = blk >> 7;
    int tile = blk & 127;
    int tx0 = (tile & 7) << 6;
    int ty0 = (tile >> 3) << 5;
    int u = threadIdx.x;
    int half = u >> 7;      // 0: max map (bc + Vmax), 1: min map (dc)
    int v = u & 127;
    int rg = v >> 4;        // 0..7  (sub row group)
    int cg = v & 15;
    int vx = cg << 2;
    int vy = rg << 2;
    float4 acc[4];
    float ainit = half ? FINF : -FINF;
#pragma unroll
    for (int i = 0; i < 4; ++i) acc[i] = make_float4(ainit, ainit, ainit, ainit);

    for (int c = 0; c < NCH; ++c) {
        const float* xp = x + (((size_t)(b * NCH + c)) << 18);
        float* outp = out + (((size_t)(b * 4 + c)) << 18);
        for (int it = u; it < ROWS1 * 16; it += 256) {
            int r = it >> 4;
            int x0 = (it & 15) << 2;
            int gy = ty0 - PAD + r;
            gy = gy < 0 ? 0 : (gy > H - 1 ? H - 1 : gy);
            const float* rowp = xp + (gy << 9);
            int gx0 = tx0 + x0;
            int aB = gx0 - 8; aB = aB < 0 ? 0 : aB;
            int bB = gx0 - 4; bB = bB < 0 ? 0 : bB;
            int dB = gx0 + 4; dB = dB > W - 4 ? W - 4 : dB;
            int eB = gx0 + 8; eB = eB > W - 4 ? W - 4 : eB;
            float4 fA = *(const float4*)(rowp + aB);
            float4 fB = *(const float4*)(rowp + bB);
            float4 fC = *(const float4*)(rowp + gx0);
            float4 fD = *(const float4*)(rowp + dB);
            float4 fE = *(const float4*)(rowp + eB);
            if (r >= PAD && r < PAD + TH1)
                *(float4*)&outp[((ty0 + r - PAD) << 9) + gx0] = fC;
            *(float4*)&sHmax[r * SHP + x0] = hquad<true>(fA, fB, fC, fD, fE);
            *(float4*)&sHmin[r * SHP + x0] = hquad<false>(fA, fB, fC, fD, fE);
        }
        __syncthreads();
        int gbase = ((ty0 + vy) << 9) + tx0 + vx;
        if (half == 0) {
            unsigned short* vp = vmaxh + (((size_t)(b * NCH + c)) << 18);
            vpool_half<true, true>(sHmax, vy, vx, acc, vp, gbase);
        } else {
            vpool_half<false, false>(sHmin, vy, vx, acc, nullptr, 0);
        }
        __syncthreads();
    }
    // ---- per-sub (4 rows x 64 cols) key maxima for screening ----
    if (half == 0) {
        float mn = FINF;
#pragma unroll
        for (int i = 0; i < 4; ++i) {
            float4 o = acc[i];
            mn = fminf(mn, fminf(fminf(o.x, o.y), fminf(o.z, o.w)));
        }
#pragma unroll
        for (int s = 1; s < 16; s <<= 1) mn = fminf(mn, __shfl_xor(mn, s));
        if (cg == 0) subkey[(BATCH + b) * NSUB + tile * 8 + rg] = ~mkey(mn);
    } else {
        float mx = -FINF;
#pragma unroll
        for (int i = 0; i < 4; ++i) {
            float4 o = acc[i];
            mx = fmaxf(mx, fmaxf(fmaxf(o.x, o.y), fmaxf(o.z, o.w)));
        }
#pragma unroll
        for (int s = 1; s < 16; s <<= 1) mx = fmaxf(mx, __shfl_xor(mx, s));
        if (cg == 0) subkey[b * NSUB + tile * 8 + rg] = mkey(mx);
    }
}

// ---------------------------------------------------------------------------
// K2: per (map,batch) pair: tau = 26th-largest per-sub key-max (1024 subs of
// 256 px). Theorem: the 26 largest sub-maxima sit at 26 distinct pixels, all
// >= tau, so {key >= tau} contains the lexicographic top-26. ALSO compacts
// the qualifying sub list (subkey >= tau) to qlist (the compaction r10
// wastefully repeated per block). One wave per pair; zeroes nCand.
__global__ __launch_bounds__(64) void tau_kernel(
    const unsigned* __restrict__ subkey, unsigned* __restrict__ tau,
    int* __restrict__ nQ, int* __restrict__ nCand, int* __restrict__ qlist) {
    int pair = blockIdx.x;
    int lane = threadIdx.x;
    const unsigned* sk = subkey + (size_t)pair * NSUB + lane * 16;
    unsigned ko[16];
    *(uint4*)&ko[0] = *(const uint4*)&sk[0];
    *(uint4*)&ko[4] = *(const uint4*)&sk[4];
    *(uint4*)&ko[8] = *(const uint4*)&sk[8];
    *(uint4*)&ko[12] = *(const uint4*)&sk[12];
    unsigned long long q[16];
#pragma unroll
    for (int j = 0; j < 16; ++j)
        q[j] = ((unsigned long long)ko[j] << 32) | (unsigned)(lane * 16 + j);
    unsigned tv = 0;
    for (int r = 0; r < K; ++r) {
        unsigned long long m0 = q[0] > q[1] ? q[0] : q[1];
        unsigned long long m1 = q[2] > q[3] ? q[2] : q[3];
        unsigned long long m2 = q[4] > q[5] ? q[4] : q[5];
        unsigned long long m3 = q[6] > q[7] ? q[6] : q[7];
        unsigned long long m4 = q[8] > q[9] ? q[8] : q[9];
        unsigned long long m5 = q[10] > q[11] ? q[10] : q[11];
        unsigned long long m6 = q[12] > q[13] ? q[12] : q[13];
        unsigned long long m7 = q[14] > q[15] ? q[14] : q[15];
        m0 = m0 > m1 ? m0 : m1;
        m2 = m2 > m3 ? m2 : m3;
        m4 = m4 > m5 ? m4 : m5;
        m6 = m6 > m7 ? m6 : m7;
        m0 = m0 > m2 ? m0 : m2;
        m4 = m4 > m6 ? m4 : m6;
        unsigned long long m = m0 > m4 ? m0 : m4;
#pragma unroll
        for (int s = 1; s < 64; s <<= 1) {
            unsigned long long o = shfl_xor_u64(m, s);
            m = o > m ? o : m;
        }
        if (r == K - 1) tv = (unsigned)(m >> 32);
#pragma unroll
        for (int j = 0; j < 16; ++j)
            if (q[j] == m) q[j] = 0;
    }
    // compact qualifying subs
    int* ql = qlist + pair * NSUB;
    unsigned long long lt = (1ull << lane) - 1ull;
    int base = 0;
#pragma unroll
    for (int j = 0; j < 16; ++j) {
        bool qq = ko[j] >= tv;
        unsigned long long mk = __ballot(qq);
        if (qq) ql[base + (int)__popcll(mk & lt)] = lane * 16 + j;
        base += (int)__popcll(mk);
    }
    if (lane == 0) {
        tau[pair] = tv;
        nQ[pair] = base;
        nCand[pair] = 0;
    }
}

// ---------------------------------------------------------------------------
// K3: recompute+select, BLOCK-per-sub (fixes r10's wave-serial latency).
// MAP=0: dc (min map, pairs 0..15). MAP=1: bc (max map, pairs 16..31).
// Per qualifying sub (4x64 px): 256 threads stage the 18-row x 16-group
// h-pool strip from L3-warm x in parallel; wave wv v-pools row wv (15
// sequential LDS rows, conflict-free); accumulate across channels in regs.
// fmax/fmin networks over the same clamped window are EXACT under any
// reassociation -> keys bitwise match pass-1 subkeys. One aggregated
// atomicAdd per block-round appends candidates with key >= tau.
template <int MAP>
__global__ __launch_bounds__(256) void recompute_select_kernel(
    const float* __restrict__ x, const unsigned* __restrict__ tau,
    const int* __restrict__ nQ, const int* __restrict__ qlist,
    int* __restrict__ nCand, unsigned long long* __restrict__ cand) {
    int blk = blockIdx.x;          // 256 = 16 batches x 16 slots
    int b = blk >> 4;
    int bslot = blk & 15;
    int pair = MAP * BATCH + b;
    int t = threadIdx.x;
    int wv = t >> 6, lane = t & 63;
    __shared__ __align__(16) float sH[18 * SHP];
    __shared__ int sW[4];
    __shared__ int sBase;
    unsigned tv = tau[pair];
    int n = nQ[pair];
    const int* ql = qlist + pair * NSUB;
    unsigned long long* cp = cand + (size_t)pair * CAP;
    const float* xb = x + (((size_t)(b * NCH)) << 18);
    int pr = wv;                   // wave wv owns sub row wv
    int pc = lane;
    for (int si = bslot; si < n; si += 16) {
        int sub = ql[si];
        int tile = sub >> 3, rg = sub & 7;
        int xs = (tile & 7) << 6;
        int ys = ((tile >> 3) << 5) + (rg << 2);
        float pv = MAP ? -FINF : FINF;
        for (int c = 0; c < NCH; ++c) {
            const float* xp = xb + (((size_t)c) << 18);
            for (int it = t; it < 18 * 16; it += 256) {
                int r = it >> 4;
                int x0 = (it & 15) << 2;
                int gy = ys - PAD + r;
                gy = gy < 0 ? 0 : (gy > H - 1 ? H - 1 : gy);
                const float* rowp = xp + (gy << 9);
                int gx0 = xs + x0;
                int aB = gx0 - 8; aB = aB < 0 ? 0 : aB;
                int bB = gx0 - 4; bB = bB < 0 ? 0 : bB;
                int dB = gx0 + 4; dB = dB > W - 4 ? W - 4 : dB;
                int eB = gx0 + 8; eB = eB > W - 4 ? W - 4 : eB;
                float4 fA = *(const float4*)(rowp + aB);
                float4 fB = *(const float4*)(rowp + bB);
                float4 fC = *(const float4*)(rowp + gx0);
                float4 fD = *(const float4*)(rowp + dB);
                float4 fE = *(const float4*)(rowp + eB);
                *(float4*)&sH[r * SHP + x0] =
                    MAP ? hquad<true>(fA, fB, fC, fD, fE)
                        : hquad<false>(fA, fB, fC, fD, fE);
            }
            __syncthreads();
            float m = sH[pr * SHP + pc];
#pragma unroll
            for (int jj = 1; jj < 15; ++jj)
                m = op<(bool)MAP>(m, sH[(pr + jj) * SHP + pc]);
            pv = op<(bool)MAP>(pv, m);
            __syncthreads();
        }
        unsigned k = MAP ? ~mkey(pv) : mkey(pv);
        bool q = k >= tv;
        unsigned long long mk = __ballot(q);
        int cnt = (int)__popcll(mk);
        if (lane == 0) sW[wv] = cnt;
        __syncthreads();
        if (t == 0) {
            int a0 = sW[0], a1 = sW[1], a2 = sW[2], a3 = sW[3];
            int tot = a0 + a1 + a2 + a3;
            sBase = tot ? atomicAdd(&nCand[pair], tot) : 0;
            sW[0] = 0; sW[1] = a0; sW[2] = a0 + a1; sW[3] = a0 + a1 + a2;
        }
        __syncthreads();
        if (q) {
            int slot = sBase + sW[wv] + (int)__popcll(mk & ((1ull << lane) - 1ull));
            int p = ((ys + pr) << 9) + xs + pc;
            if (slot < CAP)
                cp[slot] = ((unsigned long long)k << 32) | (unsigned)(0x7FFFFFFF - p);
        }
        __syncthreads();
    }
}

// ---------------------------------------------------------------------------
// K4: per-pair merge of nCand candidates -> global top-26. LDS-tiled with a
// CACHED per-thread slice max: per round only the winner's owner rescans.
// Unique u64s => equality removes exactly one entry.
// map0 (dc): A1 (argmax of per-pixel channel max, first occurrence).
// map1 (bc): the 26 indices for A2.
__global__ __launch_bounds__(256) void merge_kernel(
    const unsigned long long* __restrict__ cand, const int* __restrict__ nCand,
    const float* __restrict__ img, float* __restrict__ A1, int* __restrict__ idx2all) {
    int pair = blockIdx.x;
    int map = pair >> 4, b = pair & 15;
    int t = threadIdx.x;
    int wv = t >> 6, lane = t & 63;
    int n = nCand[pair];
    n = n < CAP ? n : CAP;
    const unsigned long long* cp = cand + (size_t)pair * CAP;
    __shared__ unsigned long long sC[LDSCAP];
    __shared__ unsigned long long sB[4];
    __shared__ unsigned long long sWin[K];
    __shared__ float sM[K];
    int ntile = (n + LDSCAP - 1) / LDSCAP;
    unsigned long long kc = 0;
    for (int tl = 0; tl < ntile; ++tl) {
        int lo = tl * LDSCAP;
        int m = n - lo; m = m > LDSCAP ? LDSCAP : m;
        for (int i = t; i < m; i += 256) sC[i] = cp[lo + i];
        if (tl > 0) kc = (t < K) ? sWin[t] : 0ull;
        __syncthreads();
        unsigned long long lm = 0;
        int slot = -1;
        for (int i = t; i < m; i += 256) {
            unsigned long long v = sC[i];
            if (v > lm) { lm = v; slot = i; }
        }
        for (int r = 0; r < K; ++r) {
            unsigned long long mm = lm > kc ? lm : kc;
#pragma unroll
            for (int s = 1; s < 64; s <<= 1) {
                unsigned long long o = shfl_xor_u64(mm, s);
                mm = o > mm ? o : mm;
            }
            if (lane == 0) sB[wv] = mm;
            __syncthreads();
            unsigned long long wb = sB[0];
            if (sB[1] > wb) wb = sB[1];
            if (sB[2] > wb) wb = sB[2];
            if (sB[3] > wb) wb = sB[3];
            if (t == 0) sWin[r] = wb;
            if (wb == lm) {                 // owner: remove + rescan own slice
                sC[slot] = 0ull;
                lm = 0; slot = -1;
                for (int i = t; i < m; i += 256) {
                    unsigned long long v = sC[i];
                    if (v > lm) { lm = v; slot = i; }
                }
            }
            if (wb == kc) kc = 0ull;
            __syncthreads();
        }
    }
    if (map == 0) {
        if (t < K) {
            int p = 0x7FFFFFFF - (int)(unsigned)(sWin[t] & 0xFFFFFFFFull);
            float m = img[(((size_t)(b * NCH + 0)) << 18) + p];
            m = fmaxf(m, img[(((size_t)(b * NCH + 1)) << 18) + p]);
            m = fmaxf(m, img[(((size_t)(b * NCH + 2)) << 18) + p]);
            sM[t] = m;
        }
        __syncthreads();
        if (t == 0) {
            float bm = -FINF;
            int bj = 0;
            for (int j = 0; j < K; ++j)
                if (sM[j] > bm) { bm = sM[j]; bj = j; }   // strict > = first occurrence
            int p = 0x7FFFFFFF - (int)(unsigned)(sWin[bj] & 0xFFFFFFFFull);
#pragma unroll
            for (int c = 0; c < NCH; ++c)
                A1[b * NCH + c] = img[(((size_t)(b * NCH + c)) << 18) + p];
        }
    } else {
        if (t < K)
            idx2all[b * K + t] = 0x7FFFFFFF - (int)(unsigned)(sWin[t] & 0xFFFFFFFFull);
    }
}

// ---------------------------------------------------------------------------
// K5: A2 (mean over ALL batches' bottom-k indices — faithful to the
// reference's batch-mixing bug), A = 0.75*A1 + 0.25*A2, d = (1 - A) + 1e-6
__global__ __launch_bounds__(256) void compute_A_kernel(
    const float* __restrict__ img, const int* __restrict__ idx2all,
    const float* __restrict__ A1, float* __restrict__ dvec) {
    int b = blockIdx.x;
    __shared__ float ssum[256];
    for (int c = 0; c < NCH; ++c) {
        float s = 0.0f;
        for (int j = threadIdx.x; j < BK; j += 256)
            s += img[(((size_t)(b * NCH + c)) << 18) + idx2all[j]];
        ssum[threadIdx.x] = s;
        __syncthreads();
        for (int st = 128; st > 0; st >>= 1) {
            if (threadIdx.x < st) ssum[threadIdx.x] += ssum[threadIdx.x + st];
            __syncthreads();
        }
        if (threadIdx.x == 0) {
            float A2 = ssum[0] / (float)BK;
            float A = 0.75f * A1[b * NCH + c] + 0.25f * A2;
            dvec[b * NCH + c] = (1.0f - A) + 1e-6f;
        }
        __syncthreads();
    }
}

// ---------------------------------------------------------------------------
// K6: t = 1 - 0.95 * min_c (1 - M_c)*r_c, streaming fp16 Vmax (25 MB read,
// 17 MB write). x-channels of out were already written by pool_maps.
__global__ __launch_bounds__(256) void final_t_kernel(
    const unsigned short* __restrict__ vmaxh, const float* __restrict__ dvec,
    float* __restrict__ out) {
    int i4 = (blockIdx.x * 256 + threadIdx.x) << 2;
    int b = i4 >> 18;
    int p = i4 & (HW - 1);
    const unsigned short* vp = vmaxh + (((size_t)(b * NCH)) << 18) + p;
    float r0 = 1.0f / dvec[b * NCH + 0];
    float r1 = 1.0f / dvec[b * NCH + 1];
    float r2 = 1.0f / dvec[b * NCH + 2];
    ushort4 v0 = *(const ushort4*)(vp);
    ushort4 v1 = *(const ushort4*)(vp + (1 << 18));
    ushort4 v2 = *(const ushort4*)(vp + (2 << 18));
    float4 t;
    t.x = 1.0f - 0.95f * fminf(fminf(fmaf(-h2f(v0.x), r0, r0), fmaf(-h2f(v1.x), r1, r1)),
                               fmaf(-h2f(v2.x), r2, r2));
    t.y = 1.0f - 0.95f * fminf(fminf(fmaf(-h2f(v0.y), r0, r0), fmaf(-h2f(v1.y), r1, r1)),
                               fmaf(-h2f(v2.y), r2, r2));
    t.z = 1.0f - 0.95f * fminf(fminf(fmaf(-h2f(v0.z), r0, r0), fmaf(-h2f(v1.z), r1, r1)),
                               fmaf(-h2f(v2.z), r2, r2));
    t.w = 1.0f - 0.95f * fminf(fminf(fmaf(-h2f(v0.w), r0, r0), fmaf(-h2f(v1.w), r1, r1)),
                               fmaf(-h2f(v2.w), r2, r2));
    *(float4*)&out[(((size_t)(b * 4 + 3)) << 18) + p] = t;
}

// ---------------------------------------------------------------------------
extern "C" void kernel_launch(void* const* d_in, const int* in_sizes, int n_in,
                              void* d_out, int out_size, void* d_ws, size_t ws_size,
                              hipStream_t stream) {
    const float* x = (const float*)d_in[0];
    float* out = (float*)d_out;

    const size_t nPix = (size_t)BATCH * HW;      // 4,194,304
    const size_t nCh = (size_t)BATCH * NCH * HW; // 12,582,912

    unsigned long long* cand = (unsigned long long*)d_ws;        // 8 MB
    unsigned short* vmaxh = (unsigned short*)(cand + (size_t)NPAIR * CAP); // 24 MB fp16
    unsigned* subkey = (unsigned*)(vmaxh + nCh);                 // [2][16][1024]
    int* qlist = (int*)(subkey + (size_t)NPAIR * NSUB);          // [32][1024]
    unsigned* tau = (unsigned*)(qlist + (size_t)NPAIR * NSUB);
    int* nQ = (int*)(tau + NPAIR);
    int* nCand = nQ + NPAIR;
    float* A1 = (float*)(nCand + NPAIR);
    int* idx2all = (int*)(A1 + BATCH * NCH);
    float* dvec = (float*)(idx2all + BK);

    pool_maps_kernel<<<BATCH * 128, 256, 0, stream>>>(x, vmaxh, subkey, out);
    tau_kernel<<<NPAIR, 64, 0, stream>>>(subkey, tau, nQ, nCand, qlist);
    recompute_select_kernel<0><<<BATCH * 16, 256, 0, stream>>>(x, tau, nQ, qlist, nCand, cand);
    recompute_select_kernel<1><<<BATCH * 16, 256, 0, stream>>>(x, tau, nQ, qlist, nCand, cand);
    merge_kernel<<<NPAIR, 256, 0, stream>>>(cand, nCand, x, A1, idx2all);
    compute_A_kernel<<<BATCH, 256, 0, stream>>>(x, idx2all, A1, dvec);
    final_t_kernel<<<(int)(nPix / 4 / 256), 256, 0, stream>>>(vmaxh, dvec, out);
}

// Round 12
// 95.941 us; speedup vs baseline: 1.2216x; 1.1153x over previous
//
#include <hip/hip_runtime.h>
#include <hip/hip_bf16.h>
#include <hip/hip_fp16.h>

// Problem constants (fixed by setup_inputs)
#define BATCH 16
#define NCH 3
#define H 512
#define W 512
#define HW (H * W)          // 262144 = 2^18
#define PAD 7
#define K 26                // int(0.0001 * 512 * 512)
#define NSUB 1024           // subs (4 rows x 64 cols = 256 px) per batch
#define NPAIR 32            // 2 maps x 16 batches
#define BK (BATCH * K)      // 416
#define CAP 32768           // candidate list capacity per pair
#define LDSCAP 6144         // merge LDS tile (48 KB)

#define TH1 16              // pool tile height
#define ROWS1 30            // TH1 + 14
#define SHP 68              // padded LDS stride for h-pool rows (64 used)

#define FINF __builtin_inff()

// monotone float->u32 key (order-preserving for all floats)
__device__ __forceinline__ unsigned mkey(float f) {
    unsigned u = __float_as_uint(f);
    unsigned m = (unsigned)(((int)u) >> 31) | 0x80000000u;
    return u ^ m;
}

__device__ __forceinline__ unsigned short f2h(float f) {
    __half h = __float2half(f);
    return *reinterpret_cast<unsigned short*>(&h);
}
__device__ __forceinline__ float h2f(unsigned short s) {
    __half h = *reinterpret_cast<__half*>(&s);
    return __half2float(h);
}

__device__ __forceinline__ unsigned long long shfl_xor_u64(unsigned long long v, int m) {
    int lo = __shfl_xor((int)(unsigned)(v & 0xFFFFFFFFull), m);
    int hi = __shfl_xor((int)(unsigned)(v >> 32), m);
    return ((unsigned long long)(unsigned)hi << 32) | (unsigned)lo;
}

template <bool MX>
__device__ __forceinline__ float op(float a, float b) { return MX ? fmaxf(a, b) : fminf(a, b); }
template <bool MX>
__device__ __forceinline__ float4 op4(float4 a, float4 b) {
    return make_float4(op<MX>(a.x, b.x), op<MX>(a.y, b.y), op<MX>(a.z, b.z), op<MX>(a.w, b.w));
}

// horizontal 15-window pool of a 4-output group from 5 clamped-base float4s
template <bool MX>
__device__ __forceinline__ float4 hquad(float4 fA, float4 fB, float4 fC, float4 fD, float4 fE) {
    float4 m4 = op4<MX>(op4<MX>(fB, fC), fD);
    float tm = op<MX>(op<MX>(m4.x, m4.y), op<MX>(m4.z, m4.w));
    return make_float4(
        op<MX>(tm, op<MX>(fA.y, op<MX>(fA.z, fA.w))),
        op<MX>(tm, op<MX>(fA.z, op<MX>(fA.w, fE.x))),
        op<MX>(tm, op<MX>(fA.w, op<MX>(fE.x, fE.y))),
        op<MX>(tm, op<MX>(fE.x, op<MX>(fE.y, fE.z))));
}

// v-pool of 2 consecutive output rows from 16 LDS rows (14-row shared core)
template <bool MX>
__device__ __forceinline__ void vpool2(const float* __restrict__ sH, int vy, int vx,
                                       float4 o[2]) {
    const float* p0 = sH + vy * SHP + vx;
    float4 t4 = *(const float4*)(p0 + SHP);
#pragma unroll
    for (int j = 2; j <= 14; ++j) t4 = op4<MX>(t4, *(const float4*)(p0 + j * SHP));
    float4 r0 = *(const float4*)(p0);
    float4 r15 = *(const float4*)(p0 + 15 * SHP);
    o[0] = op4<MX>(r0, t4);
    o[1] = op4<MX>(t4, r15);
}

// ---------------------------------------------------------------------------
// K1: r9 structure, 64x16 tiles. LDS 16.3 KB -> 8 blocks/CU, grid 4096 =
// exactly 2 full rounds (no partial-round tail). Per channel: h-pool straight
// from global (5 clamped-base float4 loads per 4-output group == exact
// clamp-to-edge), max AND min from the same loads into two LDS buffers;
// x->out copy rides on the center float4. v-pool half-split: u<128 -> max map
// (fp16 Vmax + bc keys), u>=128 -> min map (dc keys). Emits per-sub (4x64)
// key maxima for screening. Each thread owns 2 rows x 4 cols.
__global__ __launch_bounds__(256, 8) void pool_maps_kernel(
    const float* __restrict__ x, unsigned short* __restrict__ vmaxh,
    unsigned* __restrict__ dcK, unsigned* __restrict__ bcK,
    unsigned* __restrict__ subkey, float* __restrict__ out) {
    __shared__ __align__(16) float sHmax[ROWS1 * SHP];
    __shared__ __align__(16) float sHmin[ROWS1 * SHP];
    int blk = blockIdx.x;
    int b = blk >> 8;
    int tile = blk & 255;          // 8 cols x 32 rows of tiles
    int tx0 = (tile & 7) << 6;
    int ty0 = (tile >> 3) << 4;
    int u = threadIdx.x;
    int half = u >> 7;      // 0: max map (bc + Vmax), 1: min map (dc)
    int v = u & 127;
    int rg = v >> 4;        // 0..7 row-pairs
    int cg = v & 15;
    int vx = cg << 2;
    int vy = rg << 1;       // 0,2,..,14
    float4 acc[2];
    float ainit = half ? FINF : -FINF;
    acc[0] = acc[1] = make_float4(ainit, ainit, ainit, ainit);

    for (int c = 0; c < NCH; ++c) {
        const float* xp = x + (((size_t)(b * NCH + c)) << 18);
        float* outp = out + (((size_t)(b * 4 + c)) << 18);
        for (int it = u; it < ROWS1 * 16; it += 256) {
            int r = it >> 4;
            int x0 = (it & 15) << 2;
            int gy = ty0 - PAD + r;
            gy = gy < 0 ? 0 : (gy > H - 1 ? H - 1 : gy);
            const float* rowp = xp + (gy << 9);
            int gx0 = tx0 + x0;
            int aB = gx0 - 8; aB = aB < 0 ? 0 : aB;
            int bB = gx0 - 4; bB = bB < 0 ? 0 : bB;
            int dB = gx0 + 4; dB = dB > W - 4 ? W - 4 : dB;
            int eB = gx0 + 8; eB = eB > W - 4 ? W - 4 : eB;
            float4 fA = *(const float4*)(rowp + aB);
            float4 fB = *(const float4*)(rowp + bB);
            float4 fC = *(const float4*)(rowp + gx0);
            float4 fD = *(const float4*)(rowp + dB);
            float4 fE = *(const float4*)(rowp + eB);
            if (r >= PAD && r < PAD + TH1)
                *(float4*)&outp[((ty0 + r - PAD) << 9) + gx0] = fC;
            *(float4*)&sHmax[r * SHP + x0] = hquad<true>(fA, fB, fC, fD, fE);
            *(float4*)&sHmin[r * SHP + x0] = hquad<false>(fA, fB, fC, fD, fE);
        }
        __syncthreads();
        if (half == 0) {
            float4 o[2];
            vpool2<true>(sHmax, vy, vx, o);
            unsigned short* vp = vmaxh + (((size_t)(b * NCH + c)) << 18);
            int gbase = ((ty0 + vy) << 9) + tx0 + vx;
            *(ushort4*)&vp[gbase] = make_ushort4(f2h(o[0].x), f2h(o[0].y), f2h(o[0].z), f2h(o[0].w));
            *(ushort4*)&vp[gbase + 512] = make_ushort4(f2h(o[1].x), f2h(o[1].y), f2h(o[1].z), f2h(o[1].w));
            acc[0] = op4<true>(acc[0], o[0]);
            acc[1] = op4<true>(acc[1], o[1]);
        } else {
            float4 o[2];
            vpool2<false>(sHmin, vy, vx, o);
            acc[0] = op4<false>(acc[0], o[0]);
            acc[1] = op4<false>(acc[1], o[1]);
        }
        __syncthreads();
    }
    // ---- per-pixel key maps + per-sub (4 rows x 64 cols) key maxima ----
    unsigned gb = ((unsigned)b << 18) + ((ty0 + vy) << 9) + tx0 + vx;
    if (half == 0) {
        *(uint4*)&bcK[gb] =
            make_uint4(~mkey(acc[0].x), ~mkey(acc[0].y), ~mkey(acc[0].z), ~mkey(acc[0].w));
        *(uint4*)&bcK[gb + 512] =
            make_uint4(~mkey(acc[1].x), ~mkey(acc[1].y), ~mkey(acc[1].z), ~mkey(acc[1].w));
        float mn = fminf(fminf(fminf(acc[0].x, acc[0].y), fminf(acc[0].z, acc[0].w)),
                         fminf(fminf(acc[1].x, acc[1].y), fminf(acc[1].z, acc[1].w)));
#pragma unroll
        for (int s = 1; s < 32; s <<= 1) mn = fminf(mn, __shfl_xor(mn, s));
        if ((v & 31) == 0)
            subkey[(BATCH + b) * NSUB + tile * 4 + (rg >> 1)] = ~mkey(mn);
    } else {
        *(uint4*)&dcK[gb] =
            make_uint4(mkey(acc[0].x), mkey(acc[0].y), mkey(acc[0].z), mkey(acc[0].w));
        *(uint4*)&dcK[gb + 512] =
            make_uint4(mkey(acc[1].x), mkey(acc[1].y), mkey(acc[1].z), mkey(acc[1].w));
        float mx = fmaxf(fmaxf(fmaxf(acc[0].x, acc[0].y), fmaxf(acc[0].z, acc[0].w)),
                         fmaxf(fmaxf(acc[1].x, acc[1].y), fmaxf(acc[1].z, acc[1].w)));
#pragma unroll
        for (int s = 1; s < 32; s <<= 1) mx = fmaxf(mx, __shfl_xor(mx, s));
        if ((v & 31) == 0)
            subkey[b * NSUB + tile * 4 + (rg >> 1)] = mkey(mx);
    }
}

// ---------------------------------------------------------------------------
// K2: tau per (map,batch) pair = 26th-largest per-sub key-max (1024 subs of
// 256 px). Theorem: the 26 largest sub-maxima sit at 26 distinct pixels, all
// >= tau, so {key >= tau} contains the lexicographic top-26.
// One wave per pair; also zeroes the counter for K3.
__global__ __launch_bounds__(64) void tau_kernel(
    const unsigned* __restrict__ subkey, unsigned* __restrict__ tau,
    int* __restrict__ nCand) {
    int pair = blockIdx.x;
    int lane = threadIdx.x;
    const unsigned* sk = subkey + (size_t)pair * NSUB + lane * 16;
    unsigned long long q[16];
#pragma unroll
    for (int j = 0; j < 16; j += 4) {
        uint4 kq = *(const uint4*)&sk[j];
        q[j + 0] = ((unsigned long long)kq.x << 32) | (unsigned)(lane * 16 + j + 0);
        q[j + 1] = ((unsigned long long)kq.y << 32) | (unsigned)(lane * 16 + j + 1);
        q[j + 2] = ((unsigned long long)kq.z << 32) | (unsigned)(lane * 16 + j + 2);
        q[j + 3] = ((unsigned long long)kq.w << 32) | (unsigned)(lane * 16 + j + 3);
    }
    unsigned tv = 0;
    for (int r = 0; r < K; ++r) {
        unsigned long long m0 = q[0] > q[1] ? q[0] : q[1];
        unsigned long long m1 = q[2] > q[3] ? q[2] : q[3];
        unsigned long long m2 = q[4] > q[5] ? q[4] : q[5];
        unsigned long long m3 = q[6] > q[7] ? q[6] : q[7];
        unsigned long long m4 = q[8] > q[9] ? q[8] : q[9];
        unsigned long long m5 = q[10] > q[11] ? q[10] : q[11];
        unsigned long long m6 = q[12] > q[13] ? q[12] : q[13];
        unsigned long long m7 = q[14] > q[15] ? q[14] : q[15];
        m0 = m0 > m1 ? m0 : m1;
        m2 = m2 > m3 ? m2 : m3;
        m4 = m4 > m5 ? m4 : m5;
        m6 = m6 > m7 ? m6 : m7;
        m0 = m0 > m2 ? m0 : m2;
        m4 = m4 > m6 ? m4 : m6;
        unsigned long long m = m0 > m4 ? m0 : m4;
#pragma unroll
        for (int s = 1; s < 64; s <<= 1) {
            unsigned long long o = shfl_xor_u64(m, s);
            m = o > m ? o : m;
        }
        if (r == K - 1) tv = (unsigned)(m >> 32);
#pragma unroll
        for (int j = 0; j < 16; ++j)
            if (q[j] == m) q[j] = 0;
    }
    if (lane == 0) {
        tau[pair] = tv;
        nCand[pair] = 0;
    }
}

// ---------------------------------------------------------------------------
// K3: stream all 8.4M keys ([2][16][HW], dcK||bcK contiguous), append
// (key,idx)-packed u64 for every key >= tau[pair]. ONE atomicAdd per BLOCK
// (ballot masks + popcount prefixes distribute slots). Append order across
// blocks is nondeterministic; top-26 of a set is order-invariant.
__global__ __launch_bounds__(256) void filter_kernel(
    const unsigned* __restrict__ keys, const unsigned* __restrict__ tau,
    int* __restrict__ nCand, unsigned long long* __restrict__ cand) {
    int gid = blockIdx.x * 256 + threadIdx.x;
    int base = gid << 3;                 // 8 keys per thread; block = 2048 keys
    int pair = base >> 18;               // uniform per block
    unsigned tv = tau[pair];
    uint4 k0 = *(const uint4*)(keys + base);
    uint4 k1 = *(const uint4*)(keys + base + 4);
    unsigned kv[8] = {k0.x, k0.y, k0.z, k0.w, k1.x, k1.y, k1.z, k1.w};
    int lane = threadIdx.x & 63, wv = threadIdx.x >> 6;
    unsigned long long msk[8];
    int tot = 0;
#pragma unroll
    for (int j = 0; j < 8; ++j) {
        msk[j] = __ballot(kv[j] >= tv);
        tot += (int)__popcll(msk[j]);
    }
    __shared__ int sW[4];
    __shared__ int sBase;
    if (lane == 0) sW[wv] = tot;
    __syncthreads();
    if (threadIdx.x == 0) {
        int a0 = sW[0], a1 = sW[1], a2 = sW[2], a3 = sW[3];
        int bt = a0 + a1 + a2 + a3;
        sBase = bt ? atomicAdd(&nCand[pair], bt) : 0;
        sW[0] = 0; sW[1] = a0; sW[2] = a0 + a1; sW[3] = a0 + a1 + a2;
    }
    __syncthreads();
    int off = sBase + sW[wv];
    unsigned long long lt = (1ull << lane) - 1ull;
    unsigned long long* cp = cand + (size_t)pair * CAP;
#pragma unroll
    for (int j = 0; j < 8; ++j) {
        if (kv[j] >= tv) {
            int slot = off + (int)__popcll(msk[j] & lt);
            int p = (base + j) & (HW - 1);
            if (slot < CAP)
                cp[slot] = ((unsigned long long)kv[j] << 32) | (unsigned)(0x7FFFFFFF - p);
        }
        off += (int)__popcll(msk[j]);
    }
}

// ---------------------------------------------------------------------------
// K4: per-pair merge of nCand candidates -> global top-26. LDS-tiled with a
// CACHED per-thread slice max: per round only the winner's owner rescans.
// Unique u64s => equality removes exactly one entry.
// map0 (dc): A1 (argmax of per-pixel channel max, first occurrence).
// map1 (bc): the 26 indices for A2.
__global__ __launch_bounds__(256) void merge_kernel(
    const unsigned long long* __restrict__ cand, const int* __restrict__ nCand,
    const float* __restrict__ img, float* __restrict__ A1, int* __restrict__ idx2all) {
    int pair = blockIdx.x;
    int map = pair >> 4, b = pair & 15;
    int t = threadIdx.x;
    int wv = t >> 6, lane = t & 63;
    int n = nCand[pair];
    n = n < CAP ? n : CAP;
    const unsigned long long* cp = cand + (size_t)pair * CAP;
    __shared__ unsigned long long sC[LDSCAP];
    __shared__ unsigned long long sB[4];
    __shared__ unsigned long long sWin[K];
    __shared__ float sM[K];
    int ntile = (n + LDSCAP - 1) / LDSCAP;
    unsigned long long kc = 0;
    for (int tl = 0; tl < ntile; ++tl) {
        int lo = tl * LDSCAP;
        int m = n - lo; m = m > LDSCAP ? LDSCAP : m;
        for (int i = t; i < m; i += 256) sC[i] = cp[lo + i];
        if (tl > 0) kc = (t < K) ? sWin[t] : 0ull;
        __syncthreads();
        unsigned long long lm = 0;
        int slot = -1;
        for (int i = t; i < m; i += 256) {
            unsigned long long v = sC[i];
            if (v > lm) { lm = v; slot = i; }
        }
        for (int r = 0; r < K; ++r) {
            unsigned long long mm = lm > kc ? lm : kc;
#pragma unroll
            for (int s = 1; s < 64; s <<= 1) {
                unsigned long long o = shfl_xor_u64(mm, s);
                mm = o > mm ? o : mm;
            }
            if (lane == 0) sB[wv] = mm;
            __syncthreads();
            unsigned long long wb = sB[0];
            if (sB[1] > wb) wb = sB[1];
            if (sB[2] > wb) wb = sB[2];
            if (sB[3] > wb) wb = sB[3];
            if (t == 0) sWin[r] = wb;
            if (wb == lm) {                 // owner: remove + rescan own slice
                sC[slot] = 0ull;
                lm = 0; slot = -1;
                for (int i = t; i < m; i += 256) {
                    unsigned long long v = sC[i];
                    if (v > lm) { lm = v; slot = i; }
                }
            }
            if (wb == kc) kc = 0ull;
            __syncthreads();
        }
    }
    if (map == 0) {
        if (t < K) {
            int p = 0x7FFFFFFF - (int)(unsigned)(sWin[t] & 0xFFFFFFFFull);
            float m = img[(((size_t)(b * NCH + 0)) << 18) + p];
            m = fmaxf(m, img[(((size_t)(b * NCH + 1)) << 18) + p]);
            m = fmaxf(m, img[(((size_t)(b * NCH + 2)) << 18) + p]);
            sM[t] = m;
        }
        __syncthreads();
        if (t == 0) {
            float bm = -FINF;
            int bj = 0;
            for (int j = 0; j < K; ++j)
                if (sM[j] > bm) { bm = sM[j]; bj = j; }   // strict > = first occurrence
            int p = 0x7FFFFFFF - (int)(unsigned)(sWin[bj] & 0xFFFFFFFFull);
#pragma unroll
            for (int c = 0; c < NCH; ++c)
                A1[b * NCH + c] = img[(((size_t)(b * NCH + c)) << 18) + p];
        }
    } else {
        if (t < K)
            idx2all[b * K + t] = 0x7FFFFFFF - (int)(unsigned)(sWin[t] & 0xFFFFFFFFull);
    }
}

// ---------------------------------------------------------------------------
// K5: A2 (mean over ALL batches' bottom-k indices — faithful to the
// reference's batch-mixing bug), A = 0.75*A1 + 0.25*A2, d = (1 - A) + 1e-6
__global__ __launch_bounds__(256) void compute_A_kernel(
    const float* __restrict__ img, const int* __restrict__ idx2all,
    const float* __restrict__ A1, float* __restrict__ dvec) {
    int b = blockIdx.x;
    __shared__ float ssum[256];
    for (int c = 0; c < NCH; ++c) {
        float s = 0.0f;
        for (int j = threadIdx.x; j < BK; j += 256)
            s += img[(((size_t)(b * NCH + c)) << 18) + idx2all[j]];
        ssum[threadIdx.x] = s;
        __syncthreads();
        for (int st = 128; st > 0; st >>= 1) {
            if (threadIdx.x < st) ssum[threadIdx.x] += ssum[threadIdx.x + st];
            __syncthreads();
        }
        if (threadIdx.x == 0) {
            float A2 = ssum[0] / (float)BK;
            float A = 0.75f * A1[b * NCH + c] + 0.25f * A2;
            dvec[b * NCH + c] = (1.0f - A) + 1e-6f;
        }
        __syncthreads();
    }
}

// ---------------------------------------------------------------------------
// K6: t = 1 - 0.95 * min_c (1 - M_c)*r_c, streaming fp16 Vmax (25 MB read,
// 17 MB write). x-channels of out were already written by pool_maps.
__global__ __launch_bounds__(256) void final_t_kernel(
    const unsigned short* __restrict__ vmaxh, const float* __restrict__ dvec,
    float* __restrict__ out) {
    int i4 = (blockIdx.x * 256 + threadIdx.x) << 2;
    int b = i4 >> 18;
    int p = i4 & (HW - 1);
    const unsigned short* vp = vmaxh + (((size_t)(b * NCH)) << 18) + p;
    float r0 = 1.0f / dvec[b * NCH + 0];
    float r1 = 1.0f / dvec[b * NCH + 1];
    float r2 = 1.0f / dvec[b * NCH + 2];
    ushort4 v0 = *(const ushort4*)(vp);
    ushort4 v1 = *(const ushort4*)(vp + (1 << 18));
    ushort4 v2 = *(const ushort4*)(vp + (2 << 18));
    float4 t;
    t.x = 1.0f - 0.95f * fminf(fminf(fmaf(-h2f(v0.x), r0, r0), fmaf(-h2f(v1.x), r1, r1)),
                               fmaf(-h2f(v2.x), r2, r2));
    t.y = 1.0f - 0.95f * fminf(fminf(fmaf(-h2f(v0.y), r0, r0), fmaf(-h2f(v1.y), r1, r1)),
                               fmaf(-h2f(v2.y), r2, r2));
    t.z = 1.0f - 0.95f * fminf(fminf(fmaf(-h2f(v0.z), r0, r0), fmaf(-h2f(v1.z), r1, r1)),
                               fmaf(-h2f(v2.z), r2, r2));
    t.w = 1.0f - 0.95f * fminf(fminf(fmaf(-h2f(v0.w), r0, r0), fmaf(-h2f(v1.w), r1, r1)),
                               fmaf(-h2f(v2.w), r2, r2));
    *(float4*)&out[(((size_t)(b * 4 + 3)) << 18) + p] = t;
}

// ---------------------------------------------------------------------------
extern "C" void kernel_launch(void* const* d_in, const int* in_sizes, int n_in,
                              void* d_out, int out_size, void* d_ws, size_t ws_size,
                              hipStream_t stream) {
    const float* x = (const float*)d_in[0];
    float* out = (float*)d_out;

    const size_t nPix = (size_t)BATCH * HW;      // 4,194,304
    const size_t nCh = (size_t)BATCH * NCH * HW; // 12,582,912

    unsigned long long* cand = (unsigned long long*)d_ws;        // 8 MB
    unsigned* dcK = (unsigned*)(cand + (size_t)NPAIR * CAP);     // 16 MB
    unsigned* bcK = dcK + nPix;                                  // 16 MB (contiguous with dcK)
    unsigned short* vmaxh = (unsigned short*)(bcK + nPix);       // 24 MB fp16
    unsigned* subkey = (unsigned*)(vmaxh + nCh);                 // [2][16][1024]
    unsigned* tau = subkey + (size_t)NPAIR * NSUB;
    int* nCand = (int*)(tau + NPAIR);
    float* A1 = (float*)(nCand + NPAIR);
    int* idx2all = (int*)(A1 + BATCH * NCH);
    float* dvec = (float*)(idx2all + BK);

    pool_maps_kernel<<<BATCH * 256, 256, 0, stream>>>(x, vmaxh, dcK, bcK, subkey, out);
    tau_kernel<<<NPAIR, 64, 0, stream>>>(subkey, tau, nCand);
    filter_kernel<<<(int)(2 * nPix / 8 / 256), 256, 0, stream>>>(dcK, tau, nCand, cand);
    merge_kernel<<<NPAIR, 256, 0, stream>>>(cand, nCand, x, A1, idx2all);
    compute_A_kernel<<<BATCH, 256, 0, stream>>>(x, idx2all, A1, dvec);
    final_t_kernel<<<(int)(nPix / 4 / 256), 256, 0, stream>>>(vmaxh, dvec, out);
}